// Round 4
// baseline (240.171 us; speedup 1.0000x reference)
//
#include <hip/hip_runtime.h>
#include <stdint.h>

#define NB 64
#define NC 512
#define NPTS 3000
#define MAXH 70
#define MAXW 40
#define HW (MAXH * MAXW)   // 2800
#define THREADS 256
#define WAVES 4
#define CPB 128            // channels per block
#define CPW (CPB / WAVES)  // 32 channels per wave
#define NV4 750            // float4 per feature row (3000 floats)
#define NV4P 768           // padded per-wave buffer (float4) -> 12288 B
#define OV4 (HW / 4)       // 700 float4 per output row
#define FIXCAP 8192

// async global -> LDS DMA, 16 B per lane (HW: wave-uniform base + lane*16)
__device__ __forceinline__ void gload_lds16(const void* g, void* l) {
    __builtin_amdgcn_global_load_lds(
        (const __attribute__((address_space(1))) uint32_t*)g,
        (__attribute__((address_space(3))) uint32_t*)l,
        16, 0, 0);
}

// reset the fixup counter (ws is NOT re-poisoned between replays)
__global__ void fm_zero_cnt(int* cnt) {
    if (threadIdx.x == 0) cnt[0] = 0;
}

__launch_bounds__(THREADS)
__global__ void fm_gather_kernel(const float* __restrict__ feat,
                                 const int* __restrict__ ys,
                                 const int* __restrict__ xs,
                                 float* __restrict__ out,
                                 int* __restrict__ fix_cnt,
                                 int* __restrict__ fix_list,
                                 int fix_cap)
{
    __shared__ int    inv_s[HW];                 // 11.2 KB, block-shared (read-only after build)
    __shared__ float4 fbuf[WAVES * 2 * NV4P];    // 96 KB: per-wave private double buffers
    __shared__ int    s_red[16];
    __shared__ int    s_par[5];

    const int blocks_per_b = NC / CPB;           // 4
    const int b   = blockIdx.x / blocks_per_b;
    const int c0  = (blockIdx.x % blocks_per_b) * CPB;
    const int tid = threadIdx.x;
    const int lane = tid & 63;
    const int w    = tid >> 6;

    const int* ysb = ys + b * NPTS;
    const int* xsb = xs + b * NPTS;
    int* ybuf = (int*)fbuf;                 // coords parked in wave0's buffers
    int* xbuf = (int*)(fbuf + NV4P);        // (dead after inv build)

    // ---- phase 0: coalesced coord load -> LDS, fused min/max; init inv ----
    int vminY = 0x7fffffff, vminX = 0x7fffffff;
    int vmaxY = -0x7fffffff, vmaxX = -0x7fffffff;
    for (int i = tid; i < NV4; i += THREADS) {
        int4 ya = ((const int4*)ysb)[i];
        int4 xa = ((const int4*)xsb)[i];
        ((int4*)ybuf)[i] = ya;
        ((int4*)xbuf)[i] = xa;
        int yv[4] = {ya.x, ya.y, ya.z, ya.w};
        int xv[4] = {xa.x, xa.y, xa.z, xa.w};
#pragma unroll
        for (int j = 0; j < 4; ++j) {
            if (yv[j] > -1) {
                vminY = min(vminY, yv[j]); vmaxY = max(vmaxY, yv[j]);
                vminX = min(vminX, xv[j]); vmaxX = max(vmaxX, xv[j]);
            }
        }
    }
    for (int i = tid; i < HW; i += THREADS) inv_s[i] = -1;
#pragma unroll
    for (int off = 32; off > 0; off >>= 1) {
        vminY = min(vminY, __shfl_xor(vminY, off));
        vmaxY = max(vmaxY, __shfl_xor(vmaxY, off));
        vminX = min(vminX, __shfl_xor(vminX, off));
        vmaxX = max(vmaxX, __shfl_xor(vmaxX, off));
    }
    if (lane == 0) {
        s_red[w]      = vminY;
        s_red[4  + w] = vmaxY;
        s_red[8  + w] = vminX;
        s_red[12 + w] = vmaxX;
    }
    __syncthreads();
    if (tid == 0) {
        int mnY = min(min(s_red[0], s_red[1]),   min(s_red[2],  s_red[3]));
        int mxY = max(max(s_red[4], s_red[5]),   max(s_red[6],  s_red[7]));
        int mnX = min(min(s_red[8], s_red[9]),   min(s_red[10], s_red[11]));
        int mxX = max(max(s_red[12], s_red[13]), max(s_red[14], s_red[15]));
        int h = mxY - mnY + 1;
        int w_ = mxX - mnX + 1;
        int swap = (w_ > h) ? 1 : 0;
        int H0 = swap ? w_ : h;
        int W0 = swap ? h : w_;
        int h_dif = H0 - MAXH;
        int w_dif = W0 - MAXW;
        int cut_top  = (h_dif > 0) ? (h_dif + 1) / 2 : 0;
        int pad_top  = (h_dif > 0) ? 0 : (-h_dif + 1) / 2;
        int cut_left = (w_dif > 0) ? (w_dif + 1) / 2 : 0;
        int left_pad = (w_dif > 0) ? 0 : (-w_dif + 1) / 2;  // ref pads "right" on the LEFT
        s_par[0] = swap;
        s_par[1] = mnY;
        s_par[2] = mnX;
        s_par[3] = pad_top - cut_top;
        s_par[4] = left_pad - cut_left;
    }
    __syncthreads();

    // ---- phase 1: build inverse map from LDS coords ----
    {
        const int swp = s_par[0], mnY = s_par[1], mnX = s_par[2];
        const int roff = s_par[3], coff = s_par[4];
        for (int n = tid; n < NPTS; n += THREADS) {
            int y = ybuf[n];
            int x = xbuf[n];
            if (y > -1) {
                int r  = swp ? (x - mnX) : (y - mnY);
                int cl = swp ? (y - mnY) : (x - mnX);
                int rr = r + roff;
                int cc = cl + coff;
                if (rr >= 0 && rr < MAXH && cc >= 0 && cc < MAXW)
                    inv_s[rr * MAXW + cc] = n;   // unique targets per setup
            }
        }
    }
    __syncthreads();   // inv ready block-wide; coord area dead -> waves go independent

    // ---- phase 2: hoist channel-invariant inv lookups to registers ----
    int nreg[11][4];
#pragma unroll
    for (int it = 0; it < 11; ++it) {
        int i4 = it * 64 + lane;
        if (i4 < OV4) {
#pragma unroll
            for (int j = 0; j < 4; ++j) nreg[it][j] = inv_s[i4 * 4 + j];
        }
    }

    float4* buf0 = fbuf + (size_t)w * 2 * NV4P;
    float4* buf1 = buf0 + NV4P;
    const int cw0 = c0 + w * CPW;   // this wave's first channel

    // prologue: DMA first channel into buf0 (tail lanes clamp source; dest is pad)
    {
        const float4* src = (const float4*)(feat + (size_t)(b * NC + cw0) * NPTS);
#pragma unroll
        for (int it = 0; it < 12; ++it) {
            int i = it * 64 + lane;
            int s = (i < NV4) ? i : (NV4 - 1);
            gload_lds16(src + s, buf0 + i);
        }
    }

    // ---- phase 3: barrier-free per-wave channel pipeline ----
    for (int ci = 0; ci < CPW; ++ci) {
        // own DMA (and previous stores) complete; no cross-wave sync
        asm volatile("s_waitcnt vmcnt(0)" ::: "memory");
        __builtin_amdgcn_sched_barrier(0);

        if (ci + 1 < CPW) {   // async-prefetch next channel into the other buffer
            const float4* src =
                (const float4*)(feat + (size_t)(b * NC + cw0 + ci + 1) * NPTS);
            float4* bnext = ((ci + 1) & 1) ? buf1 : buf0;
#pragma unroll
            for (int it = 0; it < 12; ++it) {
                int i = it * 64 + lane;
                int s = (i < NV4) ? i : (NV4 - 1);
                gload_lds16(src + s, bnext + i);
            }
        }

        const float* fp = (const float*)((ci & 1) ? buf1 : buf0);
        float4* orow = (float4*)(out + (size_t)(b * NC + cw0 + ci) * HW);
#pragma unroll
        for (int it = 0; it < 11; ++it) {
            int i4 = it * 64 + lane;
            if (i4 < OV4) {
                float4 v;
                float* vp = &v.x;
#pragma unroll
                for (int j = 0; j < 4; ++j) {
                    int n = nreg[it][j];
                    float val = 0.0f;
                    if (n >= 0) {
                        val = fp[n];
                        if (val == -1.0f) {
                            // scattered cell containing exact -1.0 -> zero whole cell
                            int pos = atomicAdd(fix_cnt, 1);
                            if (pos < fix_cap) fix_list[pos] = b * HW + i4 * 4 + j;
                        }
                    }
                    vp[j] = val;
                }
                orow[i4] = v;
            }
        }
    }
}

__global__ void fm_fixup_kernel(const int* __restrict__ fix_cnt,
                                const int* __restrict__ fix_list,
                                int fix_cap,
                                float* __restrict__ out)
{
    int count = min(fix_cnt[0], fix_cap);
    long total = (long)count * NC;
    long stride = (long)gridDim.x * blockDim.x;
    for (long t = (long)blockIdx.x * blockDim.x + threadIdx.x; t < total; t += stride) {
        int e = (int)(t / NC);
        int c = (int)(t % NC);
        int cell = fix_list[e];
        int b   = cell / HW;
        int pos = cell % HW;
        out[(size_t)(b * NC + c) * HW + pos] = 0.0f;
    }
}

extern "C" void kernel_launch(void* const* d_in, const int* in_sizes, int n_in,
                              void* d_out, int out_size, void* d_ws, size_t ws_size,
                              hipStream_t stream) {
    const float* feat = (const float*)d_in[0];
    const int*   ys   = (const int*)d_in[1];
    const int*   xs   = (const int*)d_in[2];
    float* out = (float*)d_out;

    int* fix_cnt  = (int*)d_ws;
    int* fix_list = (int*)((char*)d_ws + 16);
    int fix_cap = 0;
    if (ws_size > 16) {
        size_t avail = (ws_size - 16) / 4;
        fix_cap = (int)((avail < FIXCAP) ? avail : FIXCAP);
    }

    fm_zero_cnt<<<1, 64, 0, stream>>>(fix_cnt);

    int grid = NB * (NC / CPB);  // 64 * 4 = 256 blocks = 1 per CU
    fm_gather_kernel<<<grid, THREADS, 0, stream>>>(feat, ys, xs, out,
                                                   fix_cnt, fix_list, fix_cap);

    fm_fixup_kernel<<<128, 256, 0, stream>>>(fix_cnt, fix_list, fix_cap, out);
}

// Round 5
// 208.870 us; speedup vs baseline: 1.1499x; 1.1499x over previous
//
#include <hip/hip_runtime.h>
#include <stdint.h>

#define NB 64
#define NC 512
#define NPTS 3000
#define MAXH 70
#define MAXW 40
#define HW (MAXH * MAXW)   // 2800
#define THREADS 256
#define WAVES 4
#define CPB 128            // channels per block
#define CPW (CPB / WAVES)  // 32 channels per wave
#define NV4 750            // float4 per feature row (3000 floats)
#define NV4P 768           // padded per-wave buffer (float4) -> 12288 B
#define OV4 (HW / 4)       // 700 float4 per output row
#define FIXCAP 8192

// async global -> LDS DMA, 16 B per lane (HW: wave-uniform base + lane*16)
__device__ __forceinline__ void gload_lds16(const void* g, void* l) {
    __builtin_amdgcn_global_load_lds(
        (const __attribute__((address_space(1))) uint32_t*)g,
        (__attribute__((address_space(3))) uint32_t*)l,
        16, 0, 0);
}

// reset the fixup counter (ws is NOT re-poisoned between replays)
__global__ void fm_zero_cnt(int* cnt) {
    if (threadIdx.x == 0) cnt[0] = 0;
}

__launch_bounds__(THREADS)
__global__ void fm_gather_kernel(const float* __restrict__ feat,
                                 const int* __restrict__ ys,
                                 const int* __restrict__ xs,
                                 float* __restrict__ out,
                                 int* __restrict__ fix_cnt,
                                 int* __restrict__ fix_list,
                                 int fix_cap)
{
    __shared__ int    inv_s[HW];                 // 11.2 KB, block-shared (read-only after build)
    __shared__ float4 fbuf[WAVES * 2 * NV4P];    // 96 KB: per-wave private double buffers
    __shared__ int    s_red[16];
    __shared__ int    s_par[5];

    const int blocks_per_b = NC / CPB;           // 4
    const int b   = blockIdx.x / blocks_per_b;
    const int c0  = (blockIdx.x % blocks_per_b) * CPB;
    const int tid = threadIdx.x;
    const int lane = tid & 63;
    const int w    = tid >> 6;

    const int* ysb = ys + b * NPTS;
    const int* xsb = xs + b * NPTS;
    int* ybuf = (int*)fbuf;                 // coords parked in wave0's buffers
    int* xbuf = (int*)(fbuf + NV4P);        // (dead after inv build)

    // ---- phase 0: coalesced coord load -> LDS, fused min/max; init inv ----
    int vminY = 0x7fffffff, vminX = 0x7fffffff;
    int vmaxY = -0x7fffffff, vmaxX = -0x7fffffff;
    for (int i = tid; i < NV4; i += THREADS) {
        int4 ya = ((const int4*)ysb)[i];
        int4 xa = ((const int4*)xsb)[i];
        ((int4*)ybuf)[i] = ya;
        ((int4*)xbuf)[i] = xa;
        int yv[4] = {ya.x, ya.y, ya.z, ya.w};
        int xv[4] = {xa.x, xa.y, xa.z, xa.w};
#pragma unroll
        for (int j = 0; j < 4; ++j) {
            if (yv[j] > -1) {
                vminY = min(vminY, yv[j]); vmaxY = max(vmaxY, yv[j]);
                vminX = min(vminX, xv[j]); vmaxX = max(vmaxX, xv[j]);
            }
        }
    }
    for (int i = tid; i < HW; i += THREADS) inv_s[i] = -1;
#pragma unroll
    for (int off = 32; off > 0; off >>= 1) {
        vminY = min(vminY, __shfl_xor(vminY, off));
        vmaxY = max(vmaxY, __shfl_xor(vmaxY, off));
        vminX = min(vminX, __shfl_xor(vminX, off));
        vmaxX = max(vmaxX, __shfl_xor(vmaxX, off));
    }
    if (lane == 0) {
        s_red[w]      = vminY;
        s_red[4  + w] = vmaxY;
        s_red[8  + w] = vminX;
        s_red[12 + w] = vmaxX;
    }
    __syncthreads();
    if (tid == 0) {
        int mnY = min(min(s_red[0], s_red[1]),   min(s_red[2],  s_red[3]));
        int mxY = max(max(s_red[4], s_red[5]),   max(s_red[6],  s_red[7]));
        int mnX = min(min(s_red[8], s_red[9]),   min(s_red[10], s_red[11]));
        int mxX = max(max(s_red[12], s_red[13]), max(s_red[14], s_red[15]));
        int h = mxY - mnY + 1;
        int w_ = mxX - mnX + 1;
        int swap = (w_ > h) ? 1 : 0;
        int H0 = swap ? w_ : h;
        int W0 = swap ? h : w_;
        int h_dif = H0 - MAXH;
        int w_dif = W0 - MAXW;
        int cut_top  = (h_dif > 0) ? (h_dif + 1) / 2 : 0;
        int pad_top  = (h_dif > 0) ? 0 : (-h_dif + 1) / 2;
        int cut_left = (w_dif > 0) ? (w_dif + 1) / 2 : 0;
        int left_pad = (w_dif > 0) ? 0 : (-w_dif + 1) / 2;  // ref pads "right" on the LEFT
        s_par[0] = swap;
        s_par[1] = mnY;
        s_par[2] = mnX;
        s_par[3] = pad_top - cut_top;
        s_par[4] = left_pad - cut_left;
    }
    __syncthreads();

    // ---- phase 1: build inverse map from LDS coords ----
    {
        const int swp = s_par[0], mnY = s_par[1], mnX = s_par[2];
        const int roff = s_par[3], coff = s_par[4];
        for (int n = tid; n < NPTS; n += THREADS) {
            int y = ybuf[n];
            int x = xbuf[n];
            if (y > -1) {
                int r  = swp ? (x - mnX) : (y - mnY);
                int cl = swp ? (y - mnY) : (x - mnX);
                int rr = r + roff;
                int cc = cl + coff;
                if (rr >= 0 && rr < MAXH && cc >= 0 && cc < MAXW)
                    inv_s[rr * MAXW + cc] = n;   // unique targets per setup
            }
        }
    }
    __syncthreads();   // inv ready block-wide; coord area dead -> waves go independent

    // ---- phase 2: hoist channel-invariant inv lookups to registers ----
    int nreg[11][4];
#pragma unroll
    for (int it = 0; it < 11; ++it) {
        int i4 = it * 64 + lane;
        if (i4 < OV4) {
#pragma unroll
            for (int j = 0; j < 4; ++j) nreg[it][j] = inv_s[i4 * 4 + j];
        }
    }

    float4* buf0 = fbuf + (size_t)w * 2 * NV4P;
    float4* buf1 = buf0 + NV4P;
    const int cw0 = c0 + w * CPW;   // this wave's first channel

    // prologue: DMA first channel into buf0 (tail lanes clamp source; dest is pad)
    {
        const float4* src = (const float4*)(feat + (size_t)(b * NC + cw0) * NPTS);
#pragma unroll
        for (int it = 0; it < 12; ++it) {
            int i = it * 64 + lane;
            int s = (i < NV4) ? i : (NV4 - 1);
            gload_lds16(src + s, buf0 + i);
        }
    }

    // ---- phase 3: barrier-free per-wave channel pipeline, counted vmcnt ----
    // Per iteration this wave issues exactly: 12 gload_lds (prefetch ci+1),
    // then 11 global_store_dwordx4 (channel ci). At loop top only the 12
    // oldest ops (loads of ch ci) must be done -> vmcnt(11); stores from the
    // previous iteration remain in flight (T4: never drain to 0 in the loop).
    for (int ci = 0; ci < CPW; ++ci) {
        if (ci == 0) {
            asm volatile("s_waitcnt vmcnt(0)" ::: "memory");
        } else {
            asm volatile("s_waitcnt vmcnt(11)" ::: "memory");
        }
        __builtin_amdgcn_sched_barrier(0);

        if (ci + 1 < CPW) {   // async-prefetch next channel into the other buffer
            const float4* src =
                (const float4*)(feat + (size_t)(b * NC + cw0 + ci + 1) * NPTS);
            float4* bnext = ((ci + 1) & 1) ? buf1 : buf0;
#pragma unroll
            for (int it = 0; it < 12; ++it) {
                int i = it * 64 + lane;
                int s = (i < NV4) ? i : (NV4 - 1);
                gload_lds16(src + s, bnext + i);
            }
        }
        __builtin_amdgcn_sched_barrier(0);

        const float* fp = (const float*)((ci & 1) ? buf1 : buf0);
        float4* orow = (float4*)(out + (size_t)(b * NC + cw0 + ci) * HW);
#pragma unroll
        for (int it = 0; it < 11; ++it) {
            int i4 = it * 64 + lane;
            if (i4 < OV4) {
                float4 v;
                float* vp = &v.x;
#pragma unroll
                for (int j = 0; j < 4; ++j) {
                    int n = nreg[it][j];
                    float val = 0.0f;
                    if (n >= 0) {
                        val = fp[n];
                        if (val == -1.0f) {
                            // scattered cell containing exact -1.0 -> zero whole cell
                            int pos = atomicAdd(fix_cnt, 1);
                            if (pos < fix_cap) fix_list[pos] = b * HW + i4 * 4 + j;
                        }
                    }
                    vp[j] = val;
                }
                orow[i4] = v;
            }
        }
    }
}

__global__ void fm_fixup_kernel(const int* __restrict__ fix_cnt,
                                const int* __restrict__ fix_list,
                                int fix_cap,
                                float* __restrict__ out)
{
    int count = min(fix_cnt[0], fix_cap);
    long total = (long)count * NC;
    long stride = (long)gridDim.x * blockDim.x;
    for (long t = (long)blockIdx.x * blockDim.x + threadIdx.x; t < total; t += stride) {
        int e = (int)(t / NC);
        int c = (int)(t % NC);
        int cell = fix_list[e];
        int b   = cell / HW;
        int pos = cell % HW;
        out[(size_t)(b * NC + c) * HW + pos] = 0.0f;
    }
}

extern "C" void kernel_launch(void* const* d_in, const int* in_sizes, int n_in,
                              void* d_out, int out_size, void* d_ws, size_t ws_size,
                              hipStream_t stream) {
    const float* feat = (const float*)d_in[0];
    const int*   ys   = (const int*)d_in[1];
    const int*   xs   = (const int*)d_in[2];
    float* out = (float*)d_out;

    int* fix_cnt  = (int*)d_ws;
    int* fix_list = (int*)((char*)d_ws + 16);
    int fix_cap = 0;
    if (ws_size > 16) {
        size_t avail = (ws_size - 16) / 4;
        fix_cap = (int)((avail < FIXCAP) ? avail : FIXCAP);
    }

    fm_zero_cnt<<<1, 64, 0, stream>>>(fix_cnt);

    int grid = NB * (NC / CPB);  // 64 * 4 = 256 blocks = 1 per CU
    fm_gather_kernel<<<grid, THREADS, 0, stream>>>(feat, ys, xs, out,
                                                   fix_cnt, fix_list, fix_cap);

    fm_fixup_kernel<<<128, 256, 0, stream>>>(fix_cnt, fix_list, fix_cap, out);
}

// Round 6
// 171.371 us; speedup vs baseline: 1.4015x; 1.2188x over previous
//
#include <hip/hip_runtime.h>
#include <stdint.h>

#define NB 64
#define NC 512
#define NPTS 3000
#define MAXH 70
#define MAXW 40
#define HW (MAXH * MAXW)   // 2800
#define THREADS 256
#define CPB 32             // channels per block
#define NV4 750            // float4 per feature row (3000 floats)
#define NV4P 768           // padded buffer (float4) -> 12288 B
#define OV4 (HW / 4)       // 700 float4 per output row
#define FIXCAP 8192

// async global -> LDS DMA, 16 B per lane (HW: wave-uniform base + lane*16)
__device__ __forceinline__ void gload_lds16(const void* g, void* l) {
    __builtin_amdgcn_global_load_lds(
        (const __attribute__((address_space(1))) uint32_t*)g,
        (__attribute__((address_space(3))) uint32_t*)l,
        16, 0, 0);
}

// reset the fixup counter (ws is NOT re-poisoned between replays)
__global__ void fm_zero_cnt(int* cnt) {
    if (threadIdx.x == 0) cnt[0] = 0;
}

__launch_bounds__(THREADS)
__global__ void fm_gather_kernel(const float* __restrict__ feat,
                                 const int* __restrict__ ys,
                                 const int* __restrict__ xs,
                                 float* __restrict__ out,
                                 int* __restrict__ fix_cnt,
                                 int* __restrict__ fix_list,
                                 int fix_cap)
{
    // 3 x 12.3 KB shared channel buffers (triple-buffered pipeline).
    // Prologue aliases: tb[0]=ys, tb[1]=xs, tb[2]=inv map (all dead before use).
    __shared__ float4 tb[3][NV4P];          // 36.9 KB
    __shared__ int    s_red[16];
    __shared__ int    s_par[5];

    const int blocks_per_b = NC / CPB;      // 16
    const int b   = blockIdx.x / blocks_per_b;
    const int c0  = (blockIdx.x % blocks_per_b) * CPB;
    const int tid = threadIdx.x;
    const int lane = tid & 63;
    const int w    = tid >> 6;

    const int* ysb = ys + b * NPTS;
    const int* xsb = xs + b * NPTS;
    int* ybuf = (int*)tb[0];
    int* xbuf = (int*)tb[1];
    int* inv  = (int*)tb[2];

    // ---- phase 0: coalesced coord load -> LDS, fused min/max; init inv ----
    int vminY = 0x7fffffff, vminX = 0x7fffffff;
    int vmaxY = -0x7fffffff, vmaxX = -0x7fffffff;
    for (int i = tid; i < NV4; i += THREADS) {
        int4 ya = ((const int4*)ysb)[i];
        int4 xa = ((const int4*)xsb)[i];
        ((int4*)ybuf)[i] = ya;
        ((int4*)xbuf)[i] = xa;
        int yv[4] = {ya.x, ya.y, ya.z, ya.w};
        int xv[4] = {xa.x, xa.y, xa.z, xa.w};
#pragma unroll
        for (int j = 0; j < 4; ++j) {
            if (yv[j] > -1) {
                vminY = min(vminY, yv[j]); vmaxY = max(vmaxY, yv[j]);
                vminX = min(vminX, xv[j]); vmaxX = max(vmaxX, xv[j]);
            }
        }
    }
    for (int i = tid; i < HW; i += THREADS) inv[i] = -1;
#pragma unroll
    for (int off = 32; off > 0; off >>= 1) {
        vminY = min(vminY, __shfl_xor(vminY, off));
        vmaxY = max(vmaxY, __shfl_xor(vmaxY, off));
        vminX = min(vminX, __shfl_xor(vminX, off));
        vmaxX = max(vmaxX, __shfl_xor(vmaxX, off));
    }
    if (lane == 0) {
        s_red[w]      = vminY;
        s_red[4  + w] = vmaxY;
        s_red[8  + w] = vminX;
        s_red[12 + w] = vmaxX;
    }
    __syncthreads();
    if (tid == 0) {
        int mnY = min(min(s_red[0], s_red[1]),   min(s_red[2],  s_red[3]));
        int mxY = max(max(s_red[4], s_red[5]),   max(s_red[6],  s_red[7]));
        int mnX = min(min(s_red[8], s_red[9]),   min(s_red[10], s_red[11]));
        int mxX = max(max(s_red[12], s_red[13]), max(s_red[14], s_red[15]));
        int h  = mxY - mnY + 1;
        int w_ = mxX - mnX + 1;
        int swap = (w_ > h) ? 1 : 0;
        int H0 = swap ? w_ : h;
        int W0 = swap ? h : w_;
        int h_dif = H0 - MAXH;
        int w_dif = W0 - MAXW;
        int cut_top  = (h_dif > 0) ? (h_dif + 1) / 2 : 0;
        int pad_top  = (h_dif > 0) ? 0 : (-h_dif + 1) / 2;
        int cut_left = (w_dif > 0) ? (w_dif + 1) / 2 : 0;
        int left_pad = (w_dif > 0) ? 0 : (-w_dif + 1) / 2;  // ref pads "right" on the LEFT
        s_par[0] = swap;
        s_par[1] = mnY;
        s_par[2] = mnX;
        s_par[3] = pad_top - cut_top;
        s_par[4] = left_pad - cut_left;
    }
    __syncthreads();

    // ---- phase 1: build inverse map from LDS coords ----
    {
        const int swp = s_par[0], mnY = s_par[1], mnX = s_par[2];
        const int roff = s_par[3], coff = s_par[4];
        for (int n = tid; n < NPTS; n += THREADS) {
            int y = ybuf[n];
            int x = xbuf[n];
            if (y > -1) {
                int r  = swp ? (x - mnX) : (y - mnY);
                int cl = swp ? (y - mnY) : (x - mnX);
                int rr = r + roff;
                int cc = cl + coff;
                if (rr >= 0 && rr < MAXH && cc >= 0 && cc < MAXW)
                    inv[rr * MAXW + cc] = n;   // unique targets per setup
            }
        }
    }
    __syncthreads();

    // ---- phase 2: hoist this thread's inv entries to registers ----
    int nreg[3][4];
#pragma unroll
    for (int it = 0; it < 3; ++it) {
        int i4 = it * THREADS + tid;
        if (i4 < OV4) {
#pragma unroll
            for (int j = 0; j < 4; ++j) nreg[it][j] = inv[i4 * 4 + j];
        }
    }
    __syncthreads();   // full drain (lgkm): inv consumed; all LDS now dead

    // prologue: DMA ch0 into tb[0] (3 issues/wave; tail lanes clamp source)
    {
        const float4* src = (const float4*)(feat + (size_t)(b * NC + c0) * NPTS);
#pragma unroll
        for (int it = 0; it < 3; ++it) {
            int i = it * THREADS + tid;
            int s = (i < NV4) ? i : (NV4 - 1);
            gload_lds16(src + s, tb[0] + i);
        }
    }

    // ---- phase 3: triple-buffered pipeline, 1 raw barrier + counted vmcnt ----
    // Per iter per wave: 3 gload_lds (ch ci+1) then <=3 stores (ch ci).
    // vmcnt(5) retires loads-ci while keeping loads-ci+1 + prev stores in
    // flight (tail wave issues 2 stores -> 5 is safe-conservative).
    int cur = 0;
    for (int ci = 0; ci < CPB; ++ci) {
        const int nxt = (cur == 2) ? 0 : cur + 1;
        if (ci + 1 < CPB) {
            const float4* src =
                (const float4*)(feat + (size_t)(b * NC + c0 + ci + 1) * NPTS);
            float4* bn = tb[nxt];
#pragma unroll
            for (int it = 0; it < 3; ++it) {
                int i = it * THREADS + tid;
                int s = (i < NV4) ? i : (NV4 - 1);
                gload_lds16(src + s, bn + i);
            }
        }
        if (ci == 0) {
            asm volatile("s_waitcnt vmcnt(3)" ::: "memory");
        } else if (ci + 1 < CPB) {
            asm volatile("s_waitcnt vmcnt(5)" ::: "memory");
        } else {
            asm volatile("s_waitcnt vmcnt(2)" ::: "memory");
        }
        __builtin_amdgcn_sched_barrier(0);
        __builtin_amdgcn_s_barrier();      // all waves' loads-ci landed
        __builtin_amdgcn_sched_barrier(0);

        const float* fp = (const float*)tb[cur];
        float4* orow = (float4*)(out + (size_t)(b * NC + c0 + ci) * HW);
#pragma unroll
        for (int it = 0; it < 3; ++it) {
            int i4 = it * THREADS + tid;
            if (i4 < OV4) {
                float4 v;
                float* vp = &v.x;
#pragma unroll
                for (int j = 0; j < 4; ++j) {
                    int n = nreg[it][j];
                    float val = 0.0f;
                    if (n >= 0) {
                        val = fp[n];
                        if (val == -1.0f) {
                            // scattered cell containing exact -1.0 -> zero whole cell
                            int pos = atomicAdd(fix_cnt, 1);
                            if (pos < fix_cap) fix_list[pos] = b * HW + i4 * 4 + j;
                        }
                    }
                    vp[j] = val;
                }
                orow[i4] = v;
            }
        }
        cur = nxt;
    }
}

__global__ void fm_fixup_kernel(const int* __restrict__ fix_cnt,
                                const int* __restrict__ fix_list,
                                int fix_cap,
                                float* __restrict__ out)
{
    int count = min(fix_cnt[0], fix_cap);
    long total = (long)count * NC;
    long stride = (long)gridDim.x * blockDim.x;
    for (long t = (long)blockIdx.x * blockDim.x + threadIdx.x; t < total; t += stride) {
        int e = (int)(t / NC);
        int c = (int)(t % NC);
        int cell = fix_list[e];
        int b   = cell / HW;
        int pos = cell % HW;
        out[(size_t)(b * NC + c) * HW + pos] = 0.0f;
    }
}

extern "C" void kernel_launch(void* const* d_in, const int* in_sizes, int n_in,
                              void* d_out, int out_size, void* d_ws, size_t ws_size,
                              hipStream_t stream) {
    const float* feat = (const float*)d_in[0];
    const int*   ys   = (const int*)d_in[1];
    const int*   xs   = (const int*)d_in[2];
    float* out = (float*)d_out;

    int* fix_cnt  = (int*)d_ws;
    int* fix_list = (int*)((char*)d_ws + 16);
    int fix_cap = 0;
    if (ws_size > 16) {
        size_t avail = (ws_size - 16) / 4;
        fix_cap = (int)((avail < FIXCAP) ? avail : FIXCAP);
    }

    fm_zero_cnt<<<1, 64, 0, stream>>>(fix_cnt);

    int grid = NB * (NC / CPB);  // 64 * 16 = 1024 blocks = 4 per CU
    fm_gather_kernel<<<grid, THREADS, 0, stream>>>(feat, ys, xs, out,
                                                   fix_cnt, fix_list, fix_cap);

    fm_fixup_kernel<<<128, 256, 0, stream>>>(fix_cnt, fix_list, fix_cap, out);
}

// Round 8
// 169.347 us; speedup vs baseline: 1.4182x; 1.0120x over previous
//
#include <hip/hip_runtime.h>
#include <stdint.h>

#define NB 64
#define NC 512
#define NPTS 3000
#define MAXH 70
#define MAXW 40
#define HW (MAXH * MAXW)   // 2800
#define THREADS 256
#define CPB 32             // channels per block
#define NV4 750            // float4 per feature row (3000 floats)
#define NV4P 768           // padded buffer (float4) -> 12288 B
#define OV4 (HW / 4)       // 700 float4 per output row
#define FIXCAP 8192

typedef float f32x4 __attribute__((ext_vector_type(4)));  // native vec for NT store

// async global -> LDS DMA, 16 B per lane (HW: wave-uniform base + lane*16)
__device__ __forceinline__ void gload_lds16(const void* g, void* l) {
    __builtin_amdgcn_global_load_lds(
        (const __attribute__((address_space(1))) uint32_t*)g,
        (__attribute__((address_space(3))) uint32_t*)l,
        16, 0, 0);
}

// reset the fixup counter (ws is NOT re-poisoned between replays)
__global__ void fm_zero_cnt(int* cnt) {
    if (threadIdx.x == 0) cnt[0] = 0;
}

__launch_bounds__(THREADS)
__global__ void fm_gather_kernel(const float* __restrict__ feat,
                                 const int* __restrict__ ys,
                                 const int* __restrict__ xs,
                                 float* __restrict__ out,
                                 int* __restrict__ fix_cnt,
                                 int* __restrict__ fix_list,
                                 int fix_cap)
{
    // 3 x 12.3 KB shared channel buffers (triple-buffered pipeline).
    // Prologue aliases: tb[0]=ys, tb[1]=xs, tb[2]=inv map (all dead before use).
    __shared__ float4 tb[3][NV4P];          // 36.9 KB
    __shared__ int    s_red[16];
    __shared__ int    s_par[5];

    const int blocks_per_b = NC / CPB;      // 16
    const int b   = blockIdx.x / blocks_per_b;
    const int c0  = (blockIdx.x % blocks_per_b) * CPB;
    const int tid = threadIdx.x;
    const int lane = tid & 63;
    const int w    = tid >> 6;

    const int* ysb = ys + b * NPTS;
    const int* xsb = xs + b * NPTS;
    int* ybuf = (int*)tb[0];
    int* xbuf = (int*)tb[1];
    int* inv  = (int*)tb[2];

    // ---- phase 0: coalesced coord load -> LDS, fused min/max; init inv ----
    int vminY = 0x7fffffff, vminX = 0x7fffffff;
    int vmaxY = -0x7fffffff, vmaxX = -0x7fffffff;
    for (int i = tid; i < NV4; i += THREADS) {
        int4 ya = ((const int4*)ysb)[i];
        int4 xa = ((const int4*)xsb)[i];
        ((int4*)ybuf)[i] = ya;
        ((int4*)xbuf)[i] = xa;
        int yv[4] = {ya.x, ya.y, ya.z, ya.w};
        int xv[4] = {xa.x, xa.y, xa.z, xa.w};
#pragma unroll
        for (int j = 0; j < 4; ++j) {
            if (yv[j] > -1) {
                vminY = min(vminY, yv[j]); vmaxY = max(vmaxY, yv[j]);
                vminX = min(vminX, xv[j]); vmaxX = max(vmaxX, xv[j]);
            }
        }
    }
    for (int i = tid; i < HW; i += THREADS) inv[i] = -1;
#pragma unroll
    for (int off = 32; off > 0; off >>= 1) {
        vminY = min(vminY, __shfl_xor(vminY, off));
        vmaxY = max(vmaxY, __shfl_xor(vmaxY, off));
        vminX = min(vminX, __shfl_xor(vminX, off));
        vmaxX = max(vmaxX, __shfl_xor(vmaxX, off));
    }
    if (lane == 0) {
        s_red[w]      = vminY;
        s_red[4  + w] = vmaxY;
        s_red[8  + w] = vminX;
        s_red[12 + w] = vmaxX;
    }
    __syncthreads();
    if (tid == 0) {
        int mnY = min(min(s_red[0], s_red[1]),   min(s_red[2],  s_red[3]));
        int mxY = max(max(s_red[4], s_red[5]),   max(s_red[6],  s_red[7]));
        int mnX = min(min(s_red[8], s_red[9]),   min(s_red[10], s_red[11]));
        int mxX = max(max(s_red[12], s_red[13]), max(s_red[14], s_red[15]));
        int h  = mxY - mnY + 1;
        int w_ = mxX - mnX + 1;
        int swap = (w_ > h) ? 1 : 0;
        int H0 = swap ? w_ : h;
        int W0 = swap ? h : w_;
        int h_dif = H0 - MAXH;
        int w_dif = W0 - MAXW;
        int cut_top  = (h_dif > 0) ? (h_dif + 1) / 2 : 0;
        int pad_top  = (h_dif > 0) ? 0 : (-h_dif + 1) / 2;
        int cut_left = (w_dif > 0) ? (w_dif + 1) / 2 : 0;
        int left_pad = (w_dif > 0) ? 0 : (-w_dif + 1) / 2;  // ref pads "right" on the LEFT
        s_par[0] = swap;
        s_par[1] = mnY;
        s_par[2] = mnX;
        s_par[3] = pad_top - cut_top;
        s_par[4] = left_pad - cut_left;
    }
    __syncthreads();

    // ---- phase 1: build inverse map from LDS coords ----
    {
        const int swp = s_par[0], mnY = s_par[1], mnX = s_par[2];
        const int roff = s_par[3], coff = s_par[4];
        for (int n = tid; n < NPTS; n += THREADS) {
            int y = ybuf[n];
            int x = xbuf[n];
            if (y > -1) {
                int r  = swp ? (x - mnX) : (y - mnY);
                int cl = swp ? (y - mnY) : (x - mnX);
                int rr = r + roff;
                int cc = cl + coff;
                if (rr >= 0 && rr < MAXH && cc >= 0 && cc < MAXW)
                    inv[rr * MAXW + cc] = n;   // unique targets per setup
            }
        }
    }
    __syncthreads();

    // ---- phase 2: hoist this thread's inv entries to registers ----
    int nreg[3][4];
#pragma unroll
    for (int it = 0; it < 3; ++it) {
        int i4 = it * THREADS + tid;
        if (i4 < OV4) {
#pragma unroll
            for (int j = 0; j < 4; ++j) nreg[it][j] = inv[i4 * 4 + j];
        }
    }
    __syncthreads();   // full drain (lgkm): inv consumed; all LDS now dead

    // prologue: DMA ch0 into tb[0] (3 issues/wave; tail lanes clamp source)
    {
        const float4* src = (const float4*)(feat + (size_t)(b * NC + c0) * NPTS);
#pragma unroll
        for (int it = 0; it < 3; ++it) {
            int i = it * THREADS + tid;
            int s = (i < NV4) ? i : (NV4 - 1);
            gload_lds16(src + s, tb[0] + i);
        }
    }

    // ---- phase 3: triple-buffered pipeline, 1 raw barrier + counted vmcnt ----
    // Per iter per wave: 3 gload_lds (ch ci+1) then <=3 NT stores (ch ci).
    // vmcnt(5) retires loads-ci while keeping loads-ci+1 + prev stores in
    // flight (tail wave issues 2 stores -> 5 is safe-conservative).
    int cur = 0;
    for (int ci = 0; ci < CPB; ++ci) {
        const int nxt = (cur == 2) ? 0 : cur + 1;
        if (ci + 1 < CPB) {
            const float4* src =
                (const float4*)(feat + (size_t)(b * NC + c0 + ci + 1) * NPTS);
            float4* bn = tb[nxt];
#pragma unroll
            for (int it = 0; it < 3; ++it) {
                int i = it * THREADS + tid;
                int s = (i < NV4) ? i : (NV4 - 1);
                gload_lds16(src + s, bn + i);
            }
        }
        if (ci == 0) {
            asm volatile("s_waitcnt vmcnt(3)" ::: "memory");
        } else if (ci + 1 < CPB) {
            asm volatile("s_waitcnt vmcnt(5)" ::: "memory");
        } else {
            asm volatile("s_waitcnt vmcnt(2)" ::: "memory");
        }
        __builtin_amdgcn_sched_barrier(0);
        __builtin_amdgcn_s_barrier();      // all waves' loads-ci landed
        __builtin_amdgcn_sched_barrier(0);

        const float* fp = (const float*)tb[cur];
        f32x4* orow = (f32x4*)(out + (size_t)(b * NC + c0 + ci) * HW);
#pragma unroll
        for (int it = 0; it < 3; ++it) {
            int i4 = it * THREADS + tid;
            if (i4 < OV4) {
                f32x4 v;
#pragma unroll
                for (int j = 0; j < 4; ++j) {
                    int n = nreg[it][j];
                    float val = 0.0f;
                    if (n >= 0) {
                        val = fp[n];
                        if (val == -1.0f) {
                            // scattered cell containing exact -1.0 -> zero whole cell
                            int pos = atomicAdd(fix_cnt, 1);
                            if (pos < fix_cap) fix_list[pos] = b * HW + i4 * 4 + j;
                        }
                    }
                    v[j] = val;
                }
                // NT store: output is dead data for caches -- don't allocate
                // in L2/L3, keep features L3-resident across replays.
                __builtin_nontemporal_store(v, &orow[i4]);
            }
        }
        cur = nxt;
    }
}

__global__ void fm_fixup_kernel(const int* __restrict__ fix_cnt,
                                const int* __restrict__ fix_list,
                                int fix_cap,
                                float* __restrict__ out)
{
    int count = min(fix_cnt[0], fix_cap);
    long total = (long)count * NC;
    long stride = (long)gridDim.x * blockDim.x;
    for (long t = (long)blockIdx.x * blockDim.x + threadIdx.x; t < total; t += stride) {
        int e = (int)(t / NC);
        int c = (int)(t % NC);
        int cell = fix_list[e];
        int b   = cell / HW;
        int pos = cell % HW;
        __builtin_nontemporal_store(0.0f, &out[(size_t)(b * NC + c) * HW + pos]);
    }
}

extern "C" void kernel_launch(void* const* d_in, const int* in_sizes, int n_in,
                              void* d_out, int out_size, void* d_ws, size_t ws_size,
                              hipStream_t stream) {
    const float* feat = (const float*)d_in[0];
    const int*   ys   = (const int*)d_in[1];
    const int*   xs   = (const int*)d_in[2];
    float* out = (float*)d_out;

    int* fix_cnt  = (int*)d_ws;
    int* fix_list = (int*)((char*)d_ws + 16);
    int fix_cap = 0;
    if (ws_size > 16) {
        size_t avail = (ws_size - 16) / 4;
        fix_cap = (int)((avail < FIXCAP) ? avail : FIXCAP);
    }

    fm_zero_cnt<<<1, 64, 0, stream>>>(fix_cnt);

    int grid = NB * (NC / CPB);  // 64 * 16 = 1024 blocks = 4 per CU
    fm_gather_kernel<<<grid, THREADS, 0, stream>>>(feat, ys, xs, out,
                                                   fix_cnt, fix_list, fix_cap);

    fm_fixup_kernel<<<128, 256, 0, stream>>>(fix_cnt, fix_list, fix_cap, out);
}